// Round 2
// baseline (593.434 us; speedup 1.0000x reference)
//
#include <hip/hip_runtime.h>
#include <stdint.h>

#define F 4096
#define K_WIN 3276          // floor(0.8 * 4096)
#define BETA 1.0f
#define NT 256              // threads per block (one block per row)

// ---------- kernel A: enp[f] = exp(-BETA * prev[f]) ----------
__global__ void expneg_kernel(const float* __restrict__ prev,
                              float* __restrict__ enp) {
    int i = blockIdx.x * blockDim.x + threadIdx.x;
    if (i < F) enp[i] = expf(-BETA * prev[i]);
}

// ---------- kernel B: per-row boost + exact top-k scatter ----------
__global__ __launch_bounds__(NT) void
topk_row_kernel(const float* __restrict__ x, const float* __restrict__ enp,
                float* __restrict__ out) {
    __shared__ uint32_t lkeys[F];        // 16 KB: keys for rare tie-rank scan
    __shared__ uint32_t hist[256];       // radix histogram
    __shared__ uint32_t bc_bucket, bc_r, bc_cnt;
    __shared__ float bc_rowconst;
    __shared__ double wsum[NT / 64];

    const int t = threadIdx.x;
    const int64_t row = blockIdx.x;
    const float4* xr = (const float4*)(x + row * (int64_t)F);
    const float4* er = (const float4*)enp;
    float4* orow = (float4*)(out + row * (int64_t)F);

    // ---- load row, compute selection keys, fp64 sum of squares ----
    // thread t owns float4s at positions (t + 256*j), i.e. elems 4t+1024j+c
    uint4 ku[4];
    double s = 0.0;
#pragma unroll
    for (int j = 0; j < 4; ++j) {
        float4 xv = xr[t + NT * j];
        float4 ev = er[t + NT * j];
        s += (double)xv.x * xv.x + (double)xv.y * xv.y +
             (double)xv.z * xv.z + (double)xv.w * xv.w;
        float m0 = xv.x * ev.x, m1 = xv.y * ev.y,
              m2 = xv.z * ev.z, m3 = xv.w * ev.w;
        uint32_t u0 = __float_as_uint(m0), u1 = __float_as_uint(m1),
                 u2 = __float_as_uint(m2), u3 = __float_as_uint(m3);
        // monotone transform: order on uint == order on float
        ku[j].x = ((int32_t)u0 < 0) ? ~u0 : (u0 | 0x80000000u);
        ku[j].y = ((int32_t)u1 < 0) ? ~u1 : (u1 | 0x80000000u);
        ku[j].z = ((int32_t)u2 < 0) ? ~u2 : (u2 | 0x80000000u);
        ku[j].w = ((int32_t)u3 < 0) ? ~u3 : (u3 | 0x80000000u);
        ((uint4*)lkeys)[t + NT * j] = ku[j];
    }

    // ---- reduce sum of squares, compute row constant ----
#pragma unroll
    for (int off = 32; off > 0; off >>= 1)
        s += __shfl_down(s, off, 64);
    const int lane = t & 63, wid = t >> 6;
    if (lane == 0) wsum[wid] = s;
    __syncthreads();
    if (t == 0) {
        double tot = 0.0;
#pragma unroll
        for (int w = 0; w < NT / 64; ++w) tot += wsum[w];
        float target = (float)((double)K_WIN / sqrt(tot));
        bc_rowconst = expf(BETA * target);
    }

    // ---- exact radix select: find k-th largest key (k = K_WIN) ----
    uint32_t r = K_WIN;        // remaining rank within current candidates
    uint32_t prefBits = 0;     // resolved high bits of cutoff key
    uint32_t maskHi = 0;       // mask of resolved bits
    uint32_t cntEq = 0;        // count of keys equal to cutoff (after pass 3)
#pragma unroll
    for (int pass = 0; pass < 4; ++pass) {
        const int shift = 24 - 8 * pass;
        hist[t] = 0;
        __syncthreads();
#pragma unroll
        for (int j = 0; j < 4; ++j) {
            uint32_t kk0 = ku[j].x, kk1 = ku[j].y, kk2 = ku[j].z, kk3 = ku[j].w;
            if ((kk0 & maskHi) == prefBits) atomicAdd(&hist[(kk0 >> shift) & 0xFFu], 1u);
            if ((kk1 & maskHi) == prefBits) atomicAdd(&hist[(kk1 >> shift) & 0xFFu], 1u);
            if ((kk2 & maskHi) == prefBits) atomicAdd(&hist[(kk2 >> shift) & 0xFFu], 1u);
            if ((kk3 & maskHi) == prefBits) atomicAdd(&hist[(kk3 >> shift) & 0xFFu], 1u);
        }
        __syncthreads();
        if (t < 64) {
            // lane t covers buckets [4t, 4t+3]; suffix-scan from the top
            uint32_t h0 = hist[4 * t + 0], h1 = hist[4 * t + 1],
                     h2 = hist[4 * t + 2], h3 = hist[4 * t + 3];
            uint32_t local = h0 + h1 + h2 + h3;
            uint32_t SL = local;
#pragma unroll
            for (int off = 1; off < 64; off <<= 1) {
                uint32_t v = __shfl_down(SL, off, 64);
                if (t + off < 64) SL += v;
            }
            uint32_t Cnext = SL - local;   // count in buckets > 4t+3
            uint32_t C3 = Cnext + h3;
            uint32_t C2 = C3 + h2;
            uint32_t C1 = C2 + h1;
            uint32_t C0 = C1 + h0;
            // the bucket b with C(b+1) < r <= C(b) holds the r-th largest
            int b = -1; uint32_t nr = 0, cnt = 0;
            if      (Cnext < r && r <= C3) { b = 4 * t + 3; nr = r - Cnext; cnt = h3; }
            else if (C3    < r && r <= C2) { b = 4 * t + 2; nr = r - C3;    cnt = h2; }
            else if (C2    < r && r <= C1) { b = 4 * t + 1; nr = r - C2;    cnt = h1; }
            else if (C1    < r && r <= C0) { b = 4 * t + 0; nr = r - C1;    cnt = h0; }
            if (b >= 0) { bc_bucket = (uint32_t)b; bc_r = nr; bc_cnt = cnt; }
        }
        __syncthreads();
        prefBits |= bc_bucket << shift;
        maskHi = (uint32_t)(~((1ull << shift) - 1ull));
        r = bc_r;
        cntEq = bc_cnt;
        // no barrier needed: bc_* rewritten only after two more barriers
    }

    const uint32_t cutoff = prefBits;   // exact k-th largest key
    const uint32_t tAcc = r;            // how many == cutoff to accept (>=1)
    const bool needRank = (cntEq > tAcc);  // rare: tie straddles the cutoff
    const float rc = bc_rowconst;

    // ---- write output: accepted -> rowconst * m, else 0 ----
#pragma unroll
    for (int j = 0; j < 4; ++j) {
        float v[4];
        uint32_t kk4[4] = {ku[j].x, ku[j].y, ku[j].z, ku[j].w};
#pragma unroll
        for (int c = 0; c < 4; ++c) {
            uint32_t key = kk4[c];
            bool acc = (key > cutoff);
            if (key == cutoff) {
                if (!needRank) {
                    acc = true;   // all equals accepted
                } else {
                    // rank among equal keys by ascending index (jax tie-break)
                    int f = 1024 * j + 4 * t + c;
                    uint32_t rank = 0;
                    for (int i = 0; i < f; ++i)
                        rank += (lkeys[i] == cutoff) ? 1u : 0u;
                    acc = (rank < tAcc);
                }
            }
            // reconstruct m exactly from key (inverse monotone transform)
            uint32_t u = (key & 0x80000000u) ? (key & 0x7FFFFFFFu) : ~key;
            float m = __uint_as_float(u);
            v[c] = acc ? rc * m : 0.0f;
        }
        float4 o; o.x = v[0]; o.y = v[1]; o.z = v[2]; o.w = v[3];
        orow[t + NT * j] = o;
    }
}

extern "C" void kernel_launch(void* const* d_in, const int* in_sizes, int n_in,
                              void* d_out, int out_size, void* d_ws, size_t ws_size,
                              hipStream_t stream) {
    const float* x = (const float*)d_in[0];
    const float* prev = (const float*)d_in[1];
    float* out = (float*)d_out;
    float* enp = (float*)d_ws;   // F floats of scratch

    const int rows = in_sizes[0] / F;

    expneg_kernel<<<dim3((F + NT - 1) / NT), dim3(NT), 0, stream>>>(prev, enp);
    topk_row_kernel<<<dim3(rows), dim3(NT), 0, stream>>>(x, enp, out);
}